// Round 4
// baseline (491.435 us; speedup 1.0000x reference)
//
#include <hip/hip_runtime.h>
#include <math.h>

#define NROW 64
#define DIM  131072

// tile counts: K2 = 64 rows x 32, K3 = 64 rows x 64 (2 col-pairs each), K4 = 64 rows x 32
#define NK2 2048
#define NK3 4096
#define NK4 2048
#define T_K3 (NK2)
#define T_K4 (NK2+NK3)
#define NT_TOT (NK2+NK3+NK4)

// ---------------- complex helpers ----------------
struct cf { float x, y; };
__device__ __forceinline__ cf cadd(cf a, cf b){ return {a.x+b.x, a.y+b.y}; }
__device__ __forceinline__ cf csub(cf a, cf b){ return {a.x-b.x, a.y-b.y}; }
__device__ __forceinline__ cf cmul(cf a, cf b){ return {a.x*b.x - a.y*b.y, a.x*b.y + a.y*b.x}; }
template<int SG> __device__ __forceinline__ cf muli(cf a){
  return (SG > 0) ? cf{-a.y, a.x} : cf{a.y, -a.x};
}
__device__ __forceinline__ float sigmoidf(float x){ return 1.0f/(1.0f + __expf(-x)); }

// wave-local fence (one 64-lane wave exchanging via LDS)
__device__ __forceinline__ void wsync(){
  __builtin_amdgcn_wave_barrier();
  asm volatile("" ::: "memory");
}

typedef float __attribute__((ext_vector_type(4))) fvec4;

template<int SG> __device__ __forceinline__ void fft4(cf&a0, cf&a1, cf&a2, cf&a3){
  cf e0=cadd(a0,a2), e1=csub(a0,a2), o0=cadd(a1,a3), o1=csub(a1,a3);
  cf w=muli<SG>(o1);
  a0=cadd(e0,o0); a2=csub(e0,o0); a1=cadd(e1,w); a3=csub(e1,w);
}

template<int SG> __device__ __forceinline__ void fft8(cf v[8]){
  cf e0=v[0], e1=v[2], e2=v[4], e3=v[6];
  cf o0=v[1], o1=v[3], o2=v[5], o3=v[7];
  fft4<SG>(e0,e1,e2,e3); fft4<SG>(o0,o1,o2,o3);
  const float R=0.70710678118654752f;
  cf w1=cmul(o1, cf{R, (float)SG*R});
  cf w2=muli<SG>(o2);
  cf w3=cmul(o3, cf{-R, (float)SG*R});
  v[0]=cadd(e0,o0); v[4]=csub(e0,o0);
  v[1]=cadd(e1,w1); v[5]=csub(e1,w1);
  v[2]=cadd(e2,w2); v[6]=csub(e2,w2);
  v[3]=cadd(e3,w3); v[7]=csub(e3,w3);
}

template<int SG> __device__ __forceinline__ void fft16(cf v[16]){
  cf e[8], o[8];
  #pragma unroll
  for(int i=0;i<8;i++){ e[i]=v[2*i]; o[i]=v[2*i+1]; }
  fft8<SG>(e); fft8<SG>(o);
  const float C[8]={1.f,0.92387953251128674f,0.70710678118654752f,0.38268343236508977f,
                    0.f,-0.38268343236508977f,-0.70710678118654752f,-0.92387953251128674f};
  const float S[8]={0.f,0.38268343236508977f,0.70710678118654752f,0.92387953251128674f,
                    1.f,0.92387953251128674f,0.70710678118654752f,0.38268343236508977f};
  #pragma unroll
  for(int k=0;k<8;k++){
    cf w=cmul(o[k], cf{C[k], (float)SG*S[k]});
    v[k]=cadd(e[k],w); v[k+8]=csub(e[k],w);
  }
}

// ---------------- K0: dummy_ptr + scalar tail ----------------
__global__ void k0_tail(float* __restrict__ dout, int cplx){
  int t = threadIdx.x;
  size_t base = (size_t)2*NROW*DIM*cplx;
  if(t < NROW) dout[base + t] = 0.f;
  else if(t == NROW) dout[base + NROW] = 1.0f;
}

// ---------------- K1: global max|z| ----------------
__global__ __launch_bounds__(256) void k1_maxabs(const float* __restrict__ z, unsigned* __restrict__ dst){
  __shared__ float red[256];
  size_t i0 = (size_t)blockIdx.x*blockDim.x + threadIdx.x;
  size_t stride = (size_t)gridDim.x*blockDim.x;
  const float4* z4 = (const float4*)z;
  size_t n4 = (size_t)NROW*DIM/4;
  float m = 0.f;
  for(size_t i=i0;i<n4;i+=stride){
    float4 v=z4[i];
    m = fmaxf(m, fmaxf(fmaxf(fabsf(v.x),fabsf(v.y)), fmaxf(fabsf(v.z),fabsf(v.w))));
  }
  red[threadIdx.x]=m; __syncthreads();
  #pragma unroll
  for(int s=128;s>0;s>>=1){
    if(threadIdx.x<(unsigned)s) red[threadIdx.x]=fmaxf(red[threadIdx.x],red[threadIdx.x+s]);
    __syncthreads();
  }
  if(threadIdx.x==0) atomicMax(dst, __float_as_uint(red[0]));
}

// ================= persistent-worker sync primitives =================
// Bounded spin: if the visibility mechanism is broken this terminates (~80ms)
// with wrong results instead of hanging the container. Never triggers if sound.
__device__ __forceinline__ void wait_count(unsigned* p, unsigned need){
  if(threadIdx.x==0){
    unsigned v, tries = 0;
    do {
      v = __hip_atomic_load(p, __ATOMIC_RELAXED, __HIP_MEMORY_SCOPE_AGENT);
      if(v >= need) break;
      __builtin_amdgcn_s_sleep(8);
    } while(++tries < (1u<<19));
    // acquire: invalidate stale cache lines before the block reads produced data
    (void)__hip_atomic_load(p, __ATOMIC_ACQUIRE, __HIP_MEMORY_SCOPE_AGENT);
  }
  __syncthreads();
}
__device__ __forceinline__ void signal_done(unsigned* p){
  // __syncthreads drains vmcnt for all waves -> block's stores issued;
  // RELEASE RMW at agent scope publishes them before the count is visible.
  __syncthreads();
  if(threadIdx.x==0)
    (void)__hip_atomic_fetch_add(p, 1u, __ATOMIC_RELEASE, __HIP_MEMORY_SCOPE_AGENT);
}

// ================= stage bodies (LDS via shared union S[9856]) =================
// K2/K4 layout: reb=S[0..4383], imb=S[4384..8767], twc=S[8768..9023], tws=S[9024..9279]
// K3  layout: X cols S[0..4671] (4 x (584re+584im)), T cols S[4672..9343], twc=S[9344..9599], tws=S[9600..9855]

// ---- K2 body: forward stage-1 (FFT-256 over n2) + new_trace ----
__device__ __forceinline__ void k2_body(
    float* __restrict__ S, unsigned tile,
    const float* __restrict__ z, const float* __restrict__ tr,
    const float* __restrict__ ctrl, const unsigned* __restrict__ maxbits,
    float2* __restrict__ Bws, float* __restrict__ out_nt, int cplx)
{
  float* reb = S; float* imb = S+4384; float* twc = S+8768; float* tws = S+9024;
  int t = threadIdx.x;
  int b = tile >> 5;
  int n1b = (tile & 31) << 4;
  {
    float sv, cv;
    __sincosf(-0.0245436926061703f * (float)t, &sv, &cv); // -2*pi/256 * t
    twc[t]=cv; tws[t]=sv;
  }
  float s = 1.0f/(__uint_as_float(*maxbits) + 1e-6f);
  float gs = sigmoidf(ctrl[b*3+0]);
  float cc = gs*s;
  const float4* zr4 = (const float4*)(z  + (size_t)b*DIM);
  const float4* tr4 = (const float4*)(tr + (size_t)b*DIM);
  #pragma unroll
  for(int it=0; it<4; ++it){
    int e = t + 256*it;          // 0..1023
    int n2 = e >> 2, j4 = e & 3;
    int fi = n2*128 + (n1b>>2) + j4;
    float4 zv = zr4[fi];
    float4 tv = tr4[fi];
    int lb = n2*17 + j4*4;
    reb[lb+0]=zv.x; reb[lb+1]=zv.y; reb[lb+2]=zv.z; reb[lb+3]=zv.w;
    imb[lb+0]=tv.x; imb[lb+1]=tv.y; imb[lb+2]=tv.z; imb[lb+3]=tv.w;
    float n0 = fmaf(cc, zv.x, tv.x);
    float n1v= fmaf(cc, zv.y, tv.y);
    float n2v= fmaf(cc, zv.z, tv.z);
    float n3 = fmaf(cc, zv.w, tv.w);
    size_t n = (size_t)n2*512 + n1b + j4*4;
    size_t oidx = (size_t)b*DIM + n;
    if(cplx == 2){
      fvec4 a  = {n0, 0.f, n1v, 0.f};
      fvec4 bq = {n2v, 0.f, n3, 0.f};
      fvec4* op = (fvec4*)((float2*)out_nt + oidx);
      __builtin_nontemporal_store(a,  op);
      __builtin_nontemporal_store(bq, op+1);
    } else {
      out_nt[oidx+0]=n0; out_nt[oidx+1]=n1v; out_nt[oidx+2]=n2v; out_nt[oidx+3]=n3;
    }
  }
  __syncthreads();
  int f = t & 15, p = t >> 4;
  cf v[16];
  #pragma unroll
  for(int q=0;q<16;q++){ int n2=q*16+p; v[q].x=reb[n2*17+f]; v[q].y=imb[n2*17+f]; }
  fft16<-1>(v);
  #pragma unroll
  for(int kq=1;kq<16;kq++){ int tt=(p*kq)&255; v[kq]=cmul(v[kq], cf{twc[tt], tws[tt]}); }
  __syncthreads();
  #pragma unroll
  for(int kq=0;kq<16;kq++){ reb[f*274 + kq*17 + p]=v[kq].x; imb[f*274 + kq*17 + p]=v[kq].y; }
  __syncthreads();
  #pragma unroll
  for(int pp=0;pp<16;pp++){ v[pp].x=reb[f*274 + p*17 + pp]; v[pp].y=imb[f*274 + p*17 + pp]; }
  fft16<-1>(v);
  int nn1 = n1b + f;
  cf w, st;
  {
    float sv, cv;
    __sincosf(-4.793689960382698e-05f * (float)(nn1*p), &sv, &cv);
    w = {cv, sv};
    __sincosf(-4.793689960382698e-05f * 16.f * (float)nn1, &sv, &cv);
    st = {cv, sv};
  }
  #pragma unroll
  for(int kp=0;kp<16;kp++){
    int k2 = kp*16 + p;
    cf r = cmul(v[kp], w);
    Bws[((size_t)b<<17) + (size_t)k2*512 + nn1] = make_float2(r.x, r.y);
    w = cmul(w, st);
  }
}

// ---- fft512 over one column, one wave; half-size twiddle table (W^(t+256) = -W^t) ----
template<int SG>
__device__ __forceinline__ void fft512_block(
    float* Xre, float* Xim, float* Tre, float* Tim,
    int lane, const float* twc, const float* tws)
{
  cf v[8];
  #pragma unroll
  for(int q=0;q<8;q++){ v[q].x=Xre[q*64+lane]; v[q].y=Xim[q*64+lane]; }
  fft8<SG>(v);
  #pragma unroll
  for(int kq=1;kq<8;kq++){
    int tt=(lane*kq)&511; int ti=tt&255; float sg=(tt&256)?-1.f:1.f;
    v[kq]=cmul(v[kq], cf{sg*twc[ti], (float)SG*sg*tws[ti]});
  }
  #pragma unroll
  for(int kq=0;kq<8;kq++){ Tre[lane*9+kq]=v[kq].x; Tim[lane*9+kq]=v[kq].y; }
  wsync();
  int kQ = lane>>3, pp = lane&7;
  #pragma unroll
  for(int q=0;q<8;q++){ int idx=(q*8+pp)*9+kQ; v[q].x=Tre[idx]; v[q].y=Tim[idx]; }
  fft8<SG>(v);
  #pragma unroll
  for(int kq=1;kq<8;kq++){
    int tt=(pp*kq*8)&511; int ti=tt&255; float sg=(tt&256)?-1.f:1.f;
    v[kq]=cmul(v[kq], cf{sg*twc[ti], (float)SG*sg*tws[ti]});
  }
  wsync();
  #pragma unroll
  for(int kq=0;kq<8;kq++){ Xre[pp*73+kq*9+kQ]=v[kq].x; Xim[pp*73+kq*9+kQ]=v[kq].y; }
  wsync();
  #pragma unroll
  for(int p2=0;p2<8;p2++){ int idx=p2*73 + kQ*9 + pp; v[p2].x=Xre[idx]; v[p2].y=Xim[idx]; }
  fft8<SG>(v);
  #pragma unroll
  for(int kp=0;kp<8;kp++){ int k=kp*64 + kQ*8 + pp; Tre[k]=v[kp].x; Tim[k]=v[kp].y; }
  wsync();
}

// ---- K3 body: 4 waves = 2 column-pairs; FFT-512, Hermitian split+product, IFFT-512 ----
__device__ __forceinline__ void k3_body(
    float* __restrict__ S, unsigned r,
    float2* __restrict__ Bws, const float* __restrict__ ctrl,
    const unsigned* __restrict__ maxbits)
{
  int t = threadIdx.x;
  int b   = r >> 6;
  int idx = r & 63;
  int wp  = t >> 7;          // wave-pair 0/1
  int tt  = t & 127;
  int pr  = idx*2 + wp;      // 0..127
  int cA = (pr==0) ? 0   : pr;
  int cB = (pr==0) ? 128 : 256-pr;
  int col = tt >> 6, lane = tt & 63;
  int myc = col ? cB : cA;
  int colid = wp*2 + col;
  float* Xre = S + colid*1168;        float* Xim = Xre + 584;
  float* Tre = S + 4672 + colid*1168; float* Tim = Tre + 584;
  float* twc = S + 9344; float* tws = S + 9600;
  if(t < 256){
    float sv,cv; __sincosf(0.0122718463030851f*(float)t, &sv, &cv); // +2*pi/512, half table
    twc[t]=cv; tws[t]=sv;
  }
  float s = 1.0f/(__uint_as_float(*maxbits)+1e-6f);
  float gs = sigmoidf(ctrl[b*3+0]);
  float alpha = sigmoidf(ctrl[b*3+1]) * (1.0f/(float)DIM);
  float2* colp = Bws + ((size_t)b<<17) + ((size_t)myc<<9);
  const float4* colp4 = (const float4*)colp;
  #pragma unroll
  for(int rr=0;rr<4;rr++){
    float4 q = colp4[lane + 64*rr];
    int j = 2*(lane + 64*rr);
    Xre[j]=q.x;   Xim[j]=q.y;
    Xre[j+1]=q.z; Xim[j+1]=q.w;
  }
  __syncthreads();   // twiddle table + all column loads ready
  fft512_block<-1>(Xre, Xim, Tre, Tim, lane, twc, tws);
  __syncthreads();   // partner wave's T ready
  const float* Pre = (pr==0) ? Tre : (S + 4672 + (wp*2 + (1-col))*1168);
  const float* Pim = Pre + 584;
  #pragma unroll
  for(int rr=0;rr<8;rr++){
    int k1  = lane + 64*rr;
    int k1p = (myc==0) ? ((512-k1)&511) : (511-k1);
    float cr = Tre[k1], ci = Tim[k1];
    float qr = Pre[k1p], qi = -Pim[k1p];          // conj(C[N-k])
    float zur = 0.5f*(cr+qr), zui = 0.5f*(ci+qi);
    float dr = cr-qr, di = ci-qi;
    float tfr = 0.5f*di, tfi = -0.5f*dr;
    float szr = s*zur, szi = s*zui;
    float ntr = fmaf(gs, szr, tfr), nti = fmaf(gs, szi, tfi);
    float prr = (ntr*szr + nti*szi)*alpha;
    float pii = (nti*szr - ntr*szi)*alpha;
    Xre[k1]=prr; Xim[k1]=pii;
  }
  __syncthreads();   // partners done reading T
  fft512_block<1>(Xre, Xim, Tre, Tim, lane, twc, tws);
  cf w, st;
  {
    float sv,cv;
    __sincosf(4.793689960382698e-05f * (float)(lane*myc), &sv, &cv);
    w = {cv, sv};
    __sincosf(4.793689960382698e-05f * 64.f * (float)myc, &sv, &cv);
    st = {cv, sv};
  }
  #pragma unroll
  for(int rr=0;rr<8;rr++){
    int m1 = lane + 64*rr;
    cf r2 = cmul(cf{Tre[m1],Tim[m1]}, w);
    colp[m1] = make_float2(r2.x, r2.y);
    w = cmul(w, st);
  }
}

// ---- K4 body: inverse stage-2 (IFFT-256 over k2), write `read` ----
__device__ __forceinline__ void k4_body(
    float* __restrict__ S, unsigned r,
    const float2* __restrict__ Qws, float* __restrict__ dout, int cplx)
{
  float* reb = S; float* imb = S+4384; float* twc = S+8768; float* tws = S+9024;
  int t = threadIdx.x;
  int b = r >> 5;
  int m1b = (r & 31) << 4;
  {
    float sv, cv;
    __sincosf(0.0245436926061703f * (float)t, &sv, &cv); // +2*pi/256 * t
    twc[t]=cv; tws[t]=sv;
  }
  const float4* Qp = (const float4*)(Qws + ((size_t)b<<17));
  #pragma unroll
  for(int it=0; it<8; ++it){
    int e = t + 256*it;
    int k2 = e >> 3, j = e & 7;
    float4 q = Qp[k2*256 + (m1b>>1) + j];
    int lb = k2*17 + 2*j;
    reb[lb+0]=q.x; imb[lb+0]=q.y;
    reb[lb+1]=q.z; imb[lb+1]=q.w;
  }
  __syncthreads();
  int f = t & 15, p = t >> 4;
  cf v[16];
  #pragma unroll
  for(int q=0;q<16;q++){ int k2=q*16+p; v[q].x=reb[k2*17+f]; v[q].y=imb[k2*17+f]; }
  fft16<1>(v);
  #pragma unroll
  for(int kq=1;kq<16;kq++){ int tt=(p*kq)&255; v[kq]=cmul(v[kq], cf{twc[tt], tws[tt]}); }
  __syncthreads();
  #pragma unroll
  for(int kq=0;kq<16;kq++){ reb[f*274+kq*17+p]=v[kq].x; imb[f*274+kq*17+p]=v[kq].y; }
  __syncthreads();
  #pragma unroll
  for(int pp=0;pp<16;pp++){ v[pp].x=reb[f*274+p*17+pp]; v[pp].y=imb[f*274+p*17+pp]; }
  fft16<1>(v);
  #pragma unroll
  for(int kp=0;kp<16;kp++){
    int m2 = kp*16 + p;
    size_t n = (size_t)(m1b + f) + (size_t)512*m2;
    size_t oidx = (size_t)b*DIM + n;
    if(cplx==2) ((float2*)dout)[oidx] = make_float2(v[kp].x, 0.f);
    else dout[oidx] = v[kp].x;
  }
}

// ================= mega kernel: persistent workers + ticket queue =================
// syncw[0] = ticket head; syncw[1..64] = k2done[row]; syncw[65..128] = k3done[row]
// Deadlock-freedom: deps point only to lower tickets; tickets are grabbed in
// order by resident blocks; K2 never waits -> producers always progress.
__global__ __launch_bounds__(256) void mega(
    const float* __restrict__ z, const float* __restrict__ tr,
    const float* __restrict__ ctrl, const unsigned* __restrict__ maxbits,
    float2* __restrict__ Bws, float* __restrict__ out_nt,
    float* __restrict__ dout, int cplx, unsigned* __restrict__ syncw)
{
  __shared__ float S[9856];
  __shared__ unsigned tk_s;
  unsigned* qhead  = syncw;
  unsigned* k2done = syncw + 1;
  unsigned* k3done = syncw + 65;
  for(;;){
    __syncthreads();                 // quiesce LDS reuse across tiles
    if(threadIdx.x==0) tk_s = atomicAdd(qhead, 1u);
    __syncthreads();
    unsigned tk = tk_s;
    if(tk >= NT_TOT) break;          // uniform across block
    if(tk < T_K3){
      k2_body(S, tk, z, tr, ctrl, maxbits, Bws, out_nt, cplx);
      signal_done(&k2done[tk>>5]);
    } else if(tk < T_K4){
      unsigned r = tk - T_K3;
      wait_count(&k2done[r>>6], 32); // row's 32 K2 tiles done
      k3_body(S, r, Bws, ctrl, maxbits);
      signal_done(&k3done[r>>6]);
    } else {
      unsigned r = tk - T_K4;
      wait_count(&k3done[r>>5], 64); // row's 64 K3 tiles done
      k4_body(S, r, Bws, dout, cplx);
    }
  }
}

// ---------------- launch ----------------
extern "C" void kernel_launch(void* const* d_in, const int* in_sizes, int n_in,
                              void* d_out, int out_size, void* d_ws, size_t ws_size,
                              hipStream_t stream)
{
  (void)in_sizes; (void)n_in; (void)ws_size;
  const float* z    = (const float*)d_in[0];
  const float* tr   = (const float*)d_in[1];
  const float* ctrl = (const float*)d_in[2];
  float* dout = (float*)d_out;
  int cplx = (out_size > 20000000) ? 2 : 1;
  unsigned* maxbits = (unsigned*)d_ws;
  float2* Bws = (float2*)((char*)d_ws + 256);
  unsigned* syncw = (unsigned*)((char*)d_ws + 256 + (size_t)NROW*DIM*8); // after 64 MiB Bws

  hipMemsetAsync(d_ws, 0, 4, stream);
  hipMemsetAsync(syncw, 0, 640, stream);
  hipLaunchKernelGGL(k0_tail,  dim3(1),    dim3(128), 0, stream, dout, cplx);
  hipLaunchKernelGGL(k1_maxabs,dim3(1024), dim3(256), 0, stream, z, maxbits);
  hipLaunchKernelGGL(mega,     dim3(1024), dim3(256), 0, stream,
                     z, tr, ctrl, maxbits, Bws, dout + (size_t)NROW*DIM*cplx,
                     dout, cplx, syncw);
}

// Round 5
// 215.917 us; speedup vs baseline: 2.2760x; 2.2760x over previous
//
#include <hip/hip_runtime.h>
#include <math.h>

#define NROW 64
#define DIM  131072

// ---------------- complex helpers ----------------
struct cf { float x, y; };
__device__ __forceinline__ cf cadd(cf a, cf b){ return {a.x+b.x, a.y+b.y}; }
__device__ __forceinline__ cf csub(cf a, cf b){ return {a.x-b.x, a.y-b.y}; }
__device__ __forceinline__ cf cmul(cf a, cf b){ return {a.x*b.x - a.y*b.y, a.x*b.y + a.y*b.x}; }
template<int SG> __device__ __forceinline__ cf muli(cf a){
  return (SG > 0) ? cf{-a.y, a.x} : cf{a.y, -a.x};
}
__device__ __forceinline__ float sigmoidf(float x){ return 1.0f/(1.0f + __expf(-x)); }

// wave-local fence: one 64-lane wave exchanging via LDS. DS ops of a wave are
// processed in program order; this only stops compiler reordering.
__device__ __forceinline__ void wsync(){
  __builtin_amdgcn_wave_barrier();
  asm volatile("" ::: "memory");
}

typedef float __attribute__((ext_vector_type(4))) fvec4;

template<int SG> __device__ __forceinline__ void fft4(cf&a0, cf&a1, cf&a2, cf&a3){
  cf e0=cadd(a0,a2), e1=csub(a0,a2), o0=cadd(a1,a3), o1=csub(a1,a3);
  cf w=muli<SG>(o1);
  a0=cadd(e0,o0); a2=csub(e0,o0); a1=cadd(e1,w); a3=csub(e1,w);
}

template<int SG> __device__ __forceinline__ void fft8(cf v[8]){
  cf e0=v[0], e1=v[2], e2=v[4], e3=v[6];
  cf o0=v[1], o1=v[3], o2=v[5], o3=v[7];
  fft4<SG>(e0,e1,e2,e3); fft4<SG>(o0,o1,o2,o3);
  const float R=0.70710678118654752f;
  cf w1=cmul(o1, cf{R, (float)SG*R});
  cf w2=muli<SG>(o2);
  cf w3=cmul(o3, cf{-R, (float)SG*R});
  v[0]=cadd(e0,o0); v[4]=csub(e0,o0);
  v[1]=cadd(e1,w1); v[5]=csub(e1,w1);
  v[2]=cadd(e2,w2); v[6]=csub(e2,w2);
  v[3]=cadd(e3,w3); v[7]=csub(e3,w3);
}

template<int SG> __device__ __forceinline__ void fft16(cf v[16]){
  cf e[8], o[8];
  #pragma unroll
  for(int i=0;i<8;i++){ e[i]=v[2*i]; o[i]=v[2*i+1]; }
  fft8<SG>(e); fft8<SG>(o);
  const float C[8]={1.f,0.92387953251128674f,0.70710678118654752f,0.38268343236508977f,
                    0.f,-0.38268343236508977f,-0.70710678118654752f,-0.92387953251128674f};
  const float S[8]={0.f,0.38268343236508977f,0.70710678118654752f,0.92387953251128674f,
                    1.f,0.92387953251128674f,0.70710678118654752f,0.38268343236508977f};
  #pragma unroll
  for(int k=0;k<8;k++){
    cf w=cmul(o[k], cf{C[k], (float)SG*S[k]});
    v[k]=cadd(e[k],w); v[k+8]=csub(e[k],w);
  }
}

// ---------------- K0: dummy_ptr + scalar tail ----------------
__global__ void k0_tail(float* __restrict__ dout, int cplx){
  int t = threadIdx.x;
  size_t base = (size_t)2*NROW*DIM*cplx;
  if(t < NROW) dout[base + t] = 0.f;
  else if(t == NROW) dout[base + NROW] = 1.0f;
}

// ---------------- K1: global max|z| ----------------
__global__ __launch_bounds__(256) void k1_maxabs(const float* __restrict__ z, unsigned* __restrict__ dst){
  __shared__ float red[256];
  size_t i0 = (size_t)blockIdx.x*blockDim.x + threadIdx.x;
  size_t stride = (size_t)gridDim.x*blockDim.x;
  const float4* z4 = (const float4*)z;
  size_t n4 = (size_t)NROW*DIM/4;
  float m = 0.f;
  for(size_t i=i0;i<n4;i+=stride){
    float4 v=z4[i];
    m = fmaxf(m, fmaxf(fmaxf(fabsf(v.x),fabsf(v.y)), fmaxf(fabsf(v.z),fabsf(v.w))));
  }
  red[threadIdx.x]=m; __syncthreads();
  #pragma unroll
  for(int s=128;s>0;s>>=1){
    if(threadIdx.x<(unsigned)s) red[threadIdx.x]=fmaxf(red[threadIdx.x],red[threadIdx.x+s]);
    __syncthreads();
  }
  if(threadIdx.x==0) atomicMax(dst, __float_as_uint(red[0]));
}

// ---------------- K2: forward stage-1 (FFT-256 over n2) + new_trace ----------------
// n = n2*512 + n1. For fixed n1: B[k2][n1] = W_N^{n1*k2} * sum_{n2} c[n2*512+n1] W_256^{n2*k2}
// c = z + i*trace (unnormalized z; scale applied in K3).
__global__ __launch_bounds__(256) void k2_fwd1(
    const float* __restrict__ z, const float* __restrict__ tr,
    const float* __restrict__ ctrl, const unsigned* __restrict__ maxbits,
    float2* __restrict__ Bws, float* __restrict__ out_nt, int cplx)
{
  __shared__ float reb[4384], imb[4384];
  __shared__ float twc[256], tws[256];
  int t = threadIdx.x;
  int b = blockIdx.x >> 5;
  int n1b = (blockIdx.x & 31) << 4;
  {
    float sv, cv;
    __sincosf(-0.0245436926061703f * (float)t, &sv, &cv); // -2*pi/256 * t
    twc[t]=cv; tws[t]=sv;
  }
  float s = 1.0f/(__uint_as_float(*maxbits) + 1e-6f);
  float gs = sigmoidf(ctrl[b*3+0]);
  float cc = gs*s;
  const float4* zr4 = (const float4*)(z  + (size_t)b*DIM);
  const float4* tr4 = (const float4*)(tr + (size_t)b*DIM);
  #pragma unroll
  for(int it=0; it<4; ++it){
    int e = t + 256*it;          // 0..1023
    int n2 = e >> 2, j4 = e & 3;
    int fi = n2*128 + (n1b>>2) + j4;
    float4 zv = zr4[fi];
    float4 tv = tr4[fi];
    int lb = n2*17 + j4*4;
    reb[lb+0]=zv.x; reb[lb+1]=zv.y; reb[lb+2]=zv.z; reb[lb+3]=zv.w;
    imb[lb+0]=tv.x; imb[lb+1]=tv.y; imb[lb+2]=tv.z; imb[lb+3]=tv.w;
    float n0 = fmaf(cc, zv.x, tv.x);
    float n1v= fmaf(cc, zv.y, tv.y);
    float n2v= fmaf(cc, zv.z, tv.z);
    float n3 = fmaf(cc, zv.w, tv.w);
    size_t n = (size_t)n2*512 + n1b + j4*4;
    size_t oidx = (size_t)b*DIM + n;
    if(cplx == 2){
      fvec4 a  = {n0, 0.f, n1v, 0.f};
      fvec4 bq = {n2v, 0.f, n3, 0.f};
      fvec4* op = (fvec4*)((float2*)out_nt + oidx);
      __builtin_nontemporal_store(a,  op);
      __builtin_nontemporal_store(bq, op+1);
    } else {
      out_nt[oidx+0]=n0; out_nt[oidx+1]=n1v; out_nt[oidx+2]=n2v; out_nt[oidx+3]=n3;
    }
  }
  __syncthreads();
  int f = t & 15, p = t >> 4;
  cf v[16];
  #pragma unroll
  for(int q=0;q<16;q++){ int n2=q*16+p; v[q].x=reb[n2*17+f]; v[q].y=imb[n2*17+f]; }
  fft16<-1>(v);
  #pragma unroll
  for(int kq=1;kq<16;kq++){ int tt=(p*kq)&255; v[kq]=cmul(v[kq], cf{twc[tt], tws[tt]}); }
  __syncthreads();
  #pragma unroll
  for(int kq=0;kq<16;kq++){ reb[f*274 + kq*17 + p]=v[kq].x; imb[f*274 + kq*17 + p]=v[kq].y; }
  __syncthreads();
  #pragma unroll
  for(int pp=0;pp<16;pp++){ v[pp].x=reb[f*274 + p*17 + pp]; v[pp].y=imb[f*274 + p*17 + pp]; }
  fft16<-1>(v);
  int nn1 = n1b + f;
  cf w, st;
  {
    float sv, cv;
    __sincosf(-4.793689960382698e-05f * (float)(nn1*p), &sv, &cv);
    w = {cv, sv};
    __sincosf(-4.793689960382698e-05f * 16.f * (float)nn1, &sv, &cv);
    st = {cv, sv};
  }
  #pragma unroll
  for(int kp=0;kp<16;kp++){
    int k2 = kp*16 + p;
    cf r = cmul(v[kp], w);
    Bws[((size_t)b<<17) + (size_t)k2*512 + nn1] = make_float2(r.x, r.y);
    w = cmul(w, st);
  }
}

// ---------------- K3: one wave per 512-column, IN-PLACE FFT (no T buffer) ----------------
// In-place register-staged transposes are race-free because a single wave's DS
// ops execute in program order; wsync() only fences the compiler.
// Half twiddle table: W_512^(t+256) = -W_512^t.
template<int SG>
__device__ __forceinline__ void fft512_wave(
    float* Cre, float* Cim, int lane, const float* twc, const float* tws)
{
  cf v[8];
  int kQ = lane>>3, pp = lane&7;
  // phase 1: stride-64 butterflies
  #pragma unroll
  for(int q=0;q<8;q++){ v[q].x=Cre[q*64+lane]; v[q].y=Cim[q*64+lane]; }
  fft8<SG>(v);
  #pragma unroll
  for(int kq=1;kq<8;kq++){
    int tt=(lane*kq)&511; int ti=tt&255; float sg=(tt&256)?-1.f:1.f;
    v[kq]=cmul(v[kq], cf{sg*twc[ti], (float)SG*sg*tws[ti]});
  }
  wsync();
  #pragma unroll
  for(int kq=0;kq<8;kq++){ Cre[lane*9+kq]=v[kq].x; Cim[lane*9+kq]=v[kq].y; }
  wsync();
  // phase 2
  #pragma unroll
  for(int q=0;q<8;q++){ int idx=(q*8+pp)*9+kQ; v[q].x=Cre[idx]; v[q].y=Cim[idx]; }
  fft8<SG>(v);
  #pragma unroll
  for(int kq=1;kq<8;kq++){
    int tt=(pp*kq*8)&511; int ti=tt&255; float sg=(tt&256)?-1.f:1.f;
    v[kq]=cmul(v[kq], cf{sg*twc[ti], (float)SG*sg*tws[ti]});
  }
  wsync();
  #pragma unroll
  for(int kq=0;kq<8;kq++){ Cre[pp*73+kq*9+kQ]=v[kq].x; Cim[pp*73+kq*9+kQ]=v[kq].y; }
  wsync();
  // phase 3
  #pragma unroll
  for(int p2=0;p2<8;p2++){ int idx=p2*73 + kQ*9 + pp; v[p2].x=Cre[idx]; v[p2].y=Cim[idx]; }
  fft8<SG>(v);
  wsync();
  #pragma unroll
  for(int kp=0;kp<8;kp++){ int k=kp*64 + kQ*8 + pp; Cre[k]=v[kp].x; Cim[k]=v[kp].y; }
  wsync();
}

__global__ __launch_bounds__(128) void k3_mid(
    float2* __restrict__ Bws, const float* __restrict__ ctrl,
    const unsigned* __restrict__ maxbits)
{
  __shared__ float Cbuf[2][1168];          // per column: [re 584 | im 584]
  __shared__ float twc[256], tws[256];     // half table of W_512
  int t = threadIdx.x;
  int b  = blockIdx.x >> 7;
  int pr = blockIdx.x & 127;
  int cA = (pr==0) ? 0   : pr;
  int cB = (pr==0) ? 128 : 256-pr;
  int col = t >> 6, lane = t & 63;
  int myc = col ? cB : cA;
  for(int i=t;i<256;i+=128){
    float sv,cv; __sincosf(0.0122718463030851f*(float)i, &sv, &cv); // +2*pi/512
    twc[i]=cv; tws[i]=sv;
  }
  float s = 1.0f/(__uint_as_float(*maxbits)+1e-6f);
  float gs = sigmoidf(ctrl[b*3+0]);
  float alpha = sigmoidf(ctrl[b*3+1]) * (1.0f/(float)DIM);
  float* Cre = Cbuf[col]; float* Cim = Cre + 584;
  float2* colp = Bws + ((size_t)b<<17) + ((size_t)myc<<9);
  const float4* colp4 = (const float4*)colp;
  #pragma unroll
  for(int r=0;r<4;r++){
    float4 q = colp4[lane + 64*r];
    int j = 2*(lane + 64*r);
    Cre[j]=q.x;   Cim[j]=q.y;
    Cre[j+1]=q.z; Cim[j+1]=q.w;
  }
  __syncthreads();   // twiddle tables ready
  fft512_wave<-1>(Cre, Cim, lane, twc, tws);
  __syncthreads();   // partner wave's spectrum ready
  // Hermitian split + pointwise product, staged through registers so both
  // waves finish READING before either overwrites its buffer.
  const float* Pre = (pr==0) ? Cre : Cbuf[1-col];
  const float* Pim = Pre + 584;
  cf pv[8];
  #pragma unroll
  for(int rr=0;rr<8;rr++){
    int k1  = lane + 64*rr;
    int k1p = (myc==0) ? ((512-k1)&511) : (511-k1);
    float cr = Cre[k1], ci = Cim[k1];
    float qr = Pre[k1p], qi = -Pim[k1p];          // conj(C[N-k])
    float zur = 0.5f*(cr+qr), zui = 0.5f*(ci+qi); // Z_unnorm
    float dr = cr-qr, di = ci-qi;
    float tfr = 0.5f*di, tfi = -0.5f*dr;          // trace_f
    float szr = s*zur, szi = s*zui;               // z_f (normalized)
    float ntr = fmaf(gs, szr, tfr), nti = fmaf(gs, szi, tfi);
    pv[rr].x = (ntr*szr + nti*szi)*alpha;         // NT * conj(sZ) * retrieve/N
    pv[rr].y = (nti*szr - ntr*szi)*alpha;
  }
  __syncthreads();   // all spectrum reads complete
  #pragma unroll
  for(int rr=0;rr<8;rr++){
    int k1 = lane + 64*rr;
    Cre[k1]=pv[rr].x; Cim[k1]=pv[rr].y;
  }
  wsync();           // own-wave write->read ordering before IFFT
  fft512_wave<1>(Cre, Cim, lane, twc, tws);
  // stage twiddle W_N^{+m1*myc}: base + 7-step recurrence
  cf w, st;
  {
    float sv,cv;
    __sincosf(4.793689960382698e-05f * (float)(lane*myc), &sv, &cv);
    w = {cv, sv};
    __sincosf(4.793689960382698e-05f * 64.f * (float)myc, &sv, &cv);
    st = {cv, sv};
  }
  #pragma unroll
  for(int rr=0;rr<8;rr++){
    int m1 = lane + 64*rr;
    cf r2 = cmul(cf{Cre[m1],Cim[m1]}, w);
    colp[m1] = make_float2(r2.x, r2.y);
    w = cmul(w, st);
  }
}

// ---------------- K4: inverse stage-2 (IFFT-256 over k2), write `read` ----------------
__global__ __launch_bounds__(256) void k4_inv2(
    const float2* __restrict__ Qws, float* __restrict__ dout, int cplx)
{
  __shared__ float reb[4384], imb[4384];
  __shared__ float twc[256], tws[256];
  int t = threadIdx.x;
  int b = blockIdx.x >> 5;
  int m1b = (blockIdx.x & 31) << 4;
  {
    float sv, cv;
    __sincosf(0.0245436926061703f * (float)t, &sv, &cv); // +2*pi/256 * t
    twc[t]=cv; tws[t]=sv;
  }
  const float4* Qp = (const float4*)(Qws + ((size_t)b<<17));
  #pragma unroll
  for(int it=0; it<8; ++it){
    int e = t + 256*it;
    int k2 = e >> 3, j = e & 7;
    float4 q = Qp[k2*256 + (m1b>>1) + j];
    int lb = k2*17 + 2*j;
    reb[lb+0]=q.x; imb[lb+0]=q.y;
    reb[lb+1]=q.z; imb[lb+1]=q.w;
  }
  __syncthreads();
  int f = t & 15, p = t >> 4;
  cf v[16];
  #pragma unroll
  for(int q=0;q<16;q++){ int k2=q*16+p; v[q].x=reb[k2*17+f]; v[q].y=imb[k2*17+f]; }
  fft16<1>(v);
  #pragma unroll
  for(int kq=1;kq<16;kq++){ int tt=(p*kq)&255; v[kq]=cmul(v[kq], cf{twc[tt], tws[tt]}); }
  __syncthreads();
  #pragma unroll
  for(int kq=0;kq<16;kq++){ reb[f*274+kq*17+p]=v[kq].x; imb[f*274+kq*17+p]=v[kq].y; }
  __syncthreads();
  #pragma unroll
  for(int pp=0;pp<16;pp++){ v[pp].x=reb[f*274+p*17+pp]; v[pp].y=imb[f*274+p*17+pp]; }
  fft16<1>(v);
  #pragma unroll
  for(int kp=0;kp<16;kp++){
    int m2 = kp*16 + p;
    size_t n = (size_t)(m1b + f) + (size_t)512*m2;
    size_t oidx = (size_t)b*DIM + n;
    if(cplx==2){
      ((float2*)dout)[oidx] = make_float2(v[kp].x, 0.f);
    }
    else dout[oidx] = v[kp].x;
  }
}

// ---------------- launch ----------------
extern "C" void kernel_launch(void* const* d_in, const int* in_sizes, int n_in,
                              void* d_out, int out_size, void* d_ws, size_t ws_size,
                              hipStream_t stream)
{
  (void)in_sizes; (void)n_in; (void)ws_size;
  const float* z    = (const float*)d_in[0];
  const float* tr   = (const float*)d_in[1];
  const float* ctrl = (const float*)d_in[2];
  float* dout = (float*)d_out;
  // complex64 outputs flattened as interleaved float32 -> out_size = 2*2*B*DIM + B + 1.
  int cplx = (out_size > 20000000) ? 2 : 1;
  unsigned* maxbits = (unsigned*)d_ws;
  float2* Bws = (float2*)((char*)d_ws + 256);   // 64 MiB intermediate, in-place through K3

  hipMemsetAsync(d_ws, 0, 4, stream);
  hipLaunchKernelGGL(k0_tail,  dim3(1),    dim3(128), 0, stream, dout, cplx);
  hipLaunchKernelGGL(k1_maxabs,dim3(1024), dim3(256), 0, stream, z, maxbits);
  hipLaunchKernelGGL(k2_fwd1,  dim3(2048), dim3(256), 0, stream,
                     z, tr, ctrl, maxbits, Bws, dout + (size_t)NROW*DIM*cplx, cplx);
  hipLaunchKernelGGL(k3_mid,   dim3(8192), dim3(128), 0, stream, Bws, ctrl, maxbits);
  hipLaunchKernelGGL(k4_inv2,  dim3(2048), dim3(256), 0, stream, Bws, dout, cplx);
}

// Round 6
// 203.513 us; speedup vs baseline: 2.4148x; 1.0610x over previous
//
#include <hip/hip_runtime.h>
#include <math.h>

#define NROW 64
#define DIM  131072

// ---------------- complex helpers ----------------
struct cf { float x, y; };
__device__ __forceinline__ cf cadd(cf a, cf b){ return {a.x+b.x, a.y+b.y}; }
__device__ __forceinline__ cf csub(cf a, cf b){ return {a.x-b.x, a.y-b.y}; }
__device__ __forceinline__ cf cmul(cf a, cf b){ return {a.x*b.x - a.y*b.y, a.x*b.y + a.y*b.x}; }
template<int SG> __device__ __forceinline__ cf muli(cf a){
  return (SG > 0) ? cf{-a.y, a.x} : cf{a.y, -a.x};
}
__device__ __forceinline__ float sigmoidf(float x){ return 1.0f/(1.0f + __expf(-x)); }

// wave-local fence: one 64-lane wave exchanging via LDS. DS ops of a wave are
// processed in program order; this only stops compiler reordering.
__device__ __forceinline__ void wsync(){
  __builtin_amdgcn_wave_barrier();
  asm volatile("" ::: "memory");
}

typedef float __attribute__((ext_vector_type(4))) fvec4;

template<int SG> __device__ __forceinline__ void fft4(cf&a0, cf&a1, cf&a2, cf&a3){
  cf e0=cadd(a0,a2), e1=csub(a0,a2), o0=cadd(a1,a3), o1=csub(a1,a3);
  cf w=muli<SG>(o1);
  a0=cadd(e0,o0); a2=csub(e0,o0); a1=cadd(e1,w); a3=csub(e1,w);
}

template<int SG> __device__ __forceinline__ void fft8(cf v[8]){
  cf e0=v[0], e1=v[2], e2=v[4], e3=v[6];
  cf o0=v[1], o1=v[3], o2=v[5], o3=v[7];
  fft4<SG>(e0,e1,e2,e3); fft4<SG>(o0,o1,o2,o3);
  const float R=0.70710678118654752f;
  cf w1=cmul(o1, cf{R, (float)SG*R});
  cf w2=muli<SG>(o2);
  cf w3=cmul(o3, cf{-R, (float)SG*R});
  v[0]=cadd(e0,o0); v[4]=csub(e0,o0);
  v[1]=cadd(e1,w1); v[5]=csub(e1,w1);
  v[2]=cadd(e2,w2); v[6]=csub(e2,w2);
  v[3]=cadd(e3,w3); v[7]=csub(e3,w3);
}

template<int SG> __device__ __forceinline__ void fft16(cf v[16]){
  cf e[8], o[8];
  #pragma unroll
  for(int i=0;i<8;i++){ e[i]=v[2*i]; o[i]=v[2*i+1]; }
  fft8<SG>(e); fft8<SG>(o);
  const float C[8]={1.f,0.92387953251128674f,0.70710678118654752f,0.38268343236508977f,
                    0.f,-0.38268343236508977f,-0.70710678118654752f,-0.92387953251128674f};
  const float S[8]={0.f,0.38268343236508977f,0.70710678118654752f,0.92387953251128674f,
                    1.f,0.92387953251128674f,0.70710678118654752f,0.38268343236508977f};
  #pragma unroll
  for(int k=0;k<8;k++){
    cf w=cmul(o[k], cf{C[k], (float)SG*S[k]});
    v[k]=cadd(e[k],w); v[k+8]=csub(e[k],w);
  }
}

// ---------------- K0: dummy_ptr + scalar tail ----------------
__global__ void k0_tail(float* __restrict__ dout, int cplx){
  int t = threadIdx.x;
  size_t base = (size_t)2*NROW*DIM*cplx;
  if(t < NROW) dout[base + t] = 0.f;
  else if(t == NROW) dout[base + NROW] = 1.0f;
}

// ---------------- K1: global max|z| ----------------
__global__ __launch_bounds__(256) void k1_maxabs(const float* __restrict__ z, unsigned* __restrict__ dst){
  __shared__ float red[256];
  size_t i0 = (size_t)blockIdx.x*blockDim.x + threadIdx.x;
  size_t stride = (size_t)gridDim.x*blockDim.x;
  const float4* z4 = (const float4*)z;
  size_t n4 = (size_t)NROW*DIM/4;
  float m = 0.f;
  for(size_t i=i0;i<n4;i+=stride){
    float4 v=z4[i];
    m = fmaxf(m, fmaxf(fmaxf(fabsf(v.x),fabsf(v.y)), fmaxf(fabsf(v.z),fabsf(v.w))));
  }
  red[threadIdx.x]=m; __syncthreads();
  #pragma unroll
  for(int s=128;s>0;s>>=1){
    if(threadIdx.x<(unsigned)s) red[threadIdx.x]=fmaxf(red[threadIdx.x],red[threadIdx.x+s]);
    __syncthreads();
  }
  if(threadIdx.x==0) atomicMax(dst, __float_as_uint(red[0]));
}

// ---------------- K2: forward stage-1 (FFT-256 over n2) + new_trace ----------------
// n = n2*512 + n1. For fixed n1: B[k2][n1] = W_N^{n1*k2} * sum_{n2} c[n2*512+n1] W_256^{n2*k2}
// c = z + i*trace (unnormalized z; scale applied in K3).
__global__ __launch_bounds__(256) void k2_fwd1(
    const float* __restrict__ z, const float* __restrict__ tr,
    const float* __restrict__ ctrl, const unsigned* __restrict__ maxbits,
    float2* __restrict__ Bws, float* __restrict__ out_nt, int cplx)
{
  __shared__ float reb[4384], imb[4384];
  __shared__ float twc[256], tws[256];
  int t = threadIdx.x;
  int b = blockIdx.x >> 5;
  int n1b = (blockIdx.x & 31) << 4;
  {
    float sv, cv;
    __sincosf(-0.0245436926061703f * (float)t, &sv, &cv); // -2*pi/256 * t
    twc[t]=cv; tws[t]=sv;
  }
  float s = 1.0f/(__uint_as_float(*maxbits) + 1e-6f);
  float gs = sigmoidf(ctrl[b*3+0]);
  float cc = gs*s;
  const float4* zr4 = (const float4*)(z  + (size_t)b*DIM);
  const float4* tr4 = (const float4*)(tr + (size_t)b*DIM);
  #pragma unroll
  for(int it=0; it<4; ++it){
    int e = t + 256*it;          // 0..1023
    int n2 = e >> 2, j4 = e & 3;
    int fi = n2*128 + (n1b>>2) + j4;
    float4 zv = zr4[fi];
    float4 tv = tr4[fi];
    int lb = n2*17 + j4*4;
    reb[lb+0]=zv.x; reb[lb+1]=zv.y; reb[lb+2]=zv.z; reb[lb+3]=zv.w;
    imb[lb+0]=tv.x; imb[lb+1]=tv.y; imb[lb+2]=tv.z; imb[lb+3]=tv.w;
    float n0 = fmaf(cc, zv.x, tv.x);
    float n1v= fmaf(cc, zv.y, tv.y);
    float n2v= fmaf(cc, zv.z, tv.z);
    float n3 = fmaf(cc, zv.w, tv.w);
    size_t n = (size_t)n2*512 + n1b + j4*4;
    size_t oidx = (size_t)b*DIM + n;
    if(cplx == 2){
      fvec4 a  = {n0, 0.f, n1v, 0.f};
      fvec4 bq = {n2v, 0.f, n3, 0.f};
      fvec4* op = (fvec4*)((float2*)out_nt + oidx);
      __builtin_nontemporal_store(a,  op);
      __builtin_nontemporal_store(bq, op+1);
    } else {
      out_nt[oidx+0]=n0; out_nt[oidx+1]=n1v; out_nt[oidx+2]=n2v; out_nt[oidx+3]=n3;
    }
  }
  __syncthreads();
  int f = t & 15, p = t >> 4;
  cf v[16];
  #pragma unroll
  for(int q=0;q<16;q++){ int n2=q*16+p; v[q].x=reb[n2*17+f]; v[q].y=imb[n2*17+f]; }
  fft16<-1>(v);
  #pragma unroll
  for(int kq=1;kq<16;kq++){ int tt=(p*kq)&255; v[kq]=cmul(v[kq], cf{twc[tt], tws[tt]}); }
  __syncthreads();
  #pragma unroll
  for(int kq=0;kq<16;kq++){ reb[f*274 + kq*17 + p]=v[kq].x; imb[f*274 + kq*17 + p]=v[kq].y; }
  __syncthreads();
  #pragma unroll
  for(int pp=0;pp<16;pp++){ v[pp].x=reb[f*274 + p*17 + pp]; v[pp].y=imb[f*274 + p*17 + pp]; }
  fft16<-1>(v);
  int nn1 = n1b + f;
  cf w, st;
  {
    float sv, cv;
    __sincosf(-4.793689960382698e-05f * (float)(nn1*p), &sv, &cv);
    w = {cv, sv};
    __sincosf(-4.793689960382698e-05f * 16.f * (float)nn1, &sv, &cv);
    st = {cv, sv};
  }
  #pragma unroll
  for(int kp=0;kp<16;kp++){
    int k2 = kp*16 + p;
    cf r = cmul(v[kp], w);
    Bws[((size_t)b<<17) + (size_t)k2*512 + nn1] = make_float2(r.x, r.y);
    w = cmul(w, st);
  }
}

// ---------------- K3: row-pair packed inverse ----------------
// One wave per 512-column, in-place FFT (no T buffer); half twiddle table.
template<int SG>
__device__ __forceinline__ void fft512_wave(
    float* Cre, float* Cim, int lane, const float* twc, const float* tws)
{
  cf v[8];
  int kQ = lane>>3, pp = lane&7;
  #pragma unroll
  for(int q=0;q<8;q++){ v[q].x=Cre[q*64+lane]; v[q].y=Cim[q*64+lane]; }
  fft8<SG>(v);
  #pragma unroll
  for(int kq=1;kq<8;kq++){
    int tt=(lane*kq)&511; int ti=tt&255; float sg=(tt&256)?-1.f:1.f;
    v[kq]=cmul(v[kq], cf{sg*twc[ti], (float)SG*sg*tws[ti]});
  }
  wsync();
  #pragma unroll
  for(int kq=0;kq<8;kq++){ Cre[lane*9+kq]=v[kq].x; Cim[lane*9+kq]=v[kq].y; }
  wsync();
  #pragma unroll
  for(int q=0;q<8;q++){ int idx=(q*8+pp)*9+kQ; v[q].x=Cre[idx]; v[q].y=Cim[idx]; }
  fft8<SG>(v);
  #pragma unroll
  for(int kq=1;kq<8;kq++){
    int tt=(pp*kq*8)&511; int ti=tt&255; float sg=(tt&256)?-1.f:1.f;
    v[kq]=cmul(v[kq], cf{sg*twc[ti], (float)SG*sg*tws[ti]});
  }
  wsync();
  #pragma unroll
  for(int kq=0;kq<8;kq++){ Cre[pp*73+kq*9+kQ]=v[kq].x; Cim[pp*73+kq*9+kQ]=v[kq].y; }
  wsync();
  #pragma unroll
  for(int p2=0;p2<8;p2++){ int idx=p2*73 + kQ*9 + pp; v[p2].x=Cre[idx]; v[p2].y=Cim[idx]; }
  fft8<SG>(v);
  wsync();
  #pragma unroll
  for(int kp=0;kp<8;kp++){ int k=kp*64 + kQ*8 + pp; Cre[k]=v[kp].x; Cim[k]=v[kp].y; }
  wsync();
}

// Block = 2 waves = one (row-pair, col-pair). Each wave owns one column and
// processes BOTH rows sequentially (fwd FFT + Hermitian product -> registers),
// then combines G = R_b0 + i*R_b1 in-register (same wave, same column) and runs
// ONE inverse FFT-512 instead of two. Result stored to row b0's Bws slot.
// Linearity of the 2-stage inverse => K4's complex output y = read_b0 + i*read_b1.
__global__ __launch_bounds__(128) void k3_mid(
    float2* __restrict__ Bws, const float* __restrict__ ctrl,
    const unsigned* __restrict__ maxbits)
{
  __shared__ float Cbuf[2][1168];          // per column: [re 584 | im 584]
  __shared__ float twc[256], tws[256];     // half table of W_512
  int t = threadIdx.x;
  int bp = blockIdx.x >> 7;                // row pair 0..31
  int pr = blockIdx.x & 127;
  int b0 = bp*2, b1 = b0+1;
  int cA = (pr==0) ? 0   : pr;
  int cB = (pr==0) ? 128 : 256-pr;
  int col = t >> 6, lane = t & 63;
  int myc = col ? cB : cA;
  for(int i=t;i<256;i+=128){
    float sv,cv; __sincosf(0.0122718463030851f*(float)i, &sv, &cv); // +2*pi/512
    twc[i]=cv; tws[i]=sv;
  }
  float s = 1.0f/(__uint_as_float(*maxbits)+1e-6f);
  float gs0 = sigmoidf(ctrl[b0*3+0]);
  float al0 = sigmoidf(ctrl[b0*3+1]) * (1.0f/(float)DIM);
  float gs1 = sigmoidf(ctrl[b1*3+0]);
  float al1 = sigmoidf(ctrl[b1*3+1]) * (1.0f/(float)DIM);
  float* Cre = Cbuf[col]; float* Cim = Cre + 584;
  const float* Pre = (pr==0) ? Cre : Cbuf[1-col];
  const float* Pim = Pre + 584;
  float2* colp0 = Bws + ((size_t)b0<<17) + ((size_t)myc<<9);
  float2* colp1 = Bws + ((size_t)b1<<17) + ((size_t)myc<<9);
  cf pv0[8], pv1[8];

  // ---------- row b0: forward + Hermitian product ----------
  {
    const float4* c4 = (const float4*)colp0;
    #pragma unroll
    for(int r=0;r<4;r++){
      float4 q = c4[lane + 64*r];
      int j = 2*(lane + 64*r);
      Cre[j]=q.x;   Cim[j]=q.y;
      Cre[j+1]=q.z; Cim[j+1]=q.w;
    }
  }
  __syncthreads();   // twiddles + both columns loaded
  fft512_wave<-1>(Cre, Cim, lane, twc, tws);
  __syncthreads();   // partner spectrum ready
  #pragma unroll
  for(int rr=0;rr<8;rr++){
    int k1  = lane + 64*rr;
    int k1p = (myc==0) ? ((512-k1)&511) : (511-k1);
    float cr = Cre[k1], ci = Cim[k1];
    float qr = Pre[k1p], qi = -Pim[k1p];          // conj(C[N-k])
    float zur = 0.5f*(cr+qr), zui = 0.5f*(ci+qi); // Z_unnorm
    float dr = cr-qr, di = ci-qi;
    float tfr = 0.5f*di, tfi = -0.5f*dr;          // trace_f
    float szr = s*zur, szi = s*zui;               // z_f (normalized)
    float ntr = fmaf(gs0, szr, tfr), nti = fmaf(gs0, szi, tfi);
    pv0[rr].x = (ntr*szr + nti*szi)*al0;          // R_b0 = NT*conj(sZ)*retr/N
    pv0[rr].y = (nti*szr - ntr*szi)*al0;
  }
  __syncthreads();   // all b0 spectrum reads done before overwrite

  // ---------- row b1: forward + Hermitian product ----------
  {
    const float4* c4 = (const float4*)colp1;
    #pragma unroll
    for(int r=0;r<4;r++){
      float4 q = c4[lane + 64*r];
      int j = 2*(lane + 64*r);
      Cre[j]=q.x;   Cim[j]=q.y;
      Cre[j+1]=q.z; Cim[j+1]=q.w;
    }
  }
  wsync();
  fft512_wave<-1>(Cre, Cim, lane, twc, tws);
  __syncthreads();   // partner b1 spectrum ready
  #pragma unroll
  for(int rr=0;rr<8;rr++){
    int k1  = lane + 64*rr;
    int k1p = (myc==0) ? ((512-k1)&511) : (511-k1);
    float cr = Cre[k1], ci = Cim[k1];
    float qr = Pre[k1p], qi = -Pim[k1p];
    float zur = 0.5f*(cr+qr), zui = 0.5f*(ci+qi);
    float dr = cr-qr, di = ci-qi;
    float tfr = 0.5f*di, tfi = -0.5f*dr;
    float szr = s*zur, szi = s*zui;
    float ntr = fmaf(gs1, szr, tfr), nti = fmaf(gs1, szi, tfi);
    pv1[rr].x = (ntr*szr + nti*szi)*al1;          // R_b1
    pv1[rr].y = (nti*szr - ntr*szi)*al1;
  }
  __syncthreads();   // all b1 spectrum reads done before overwrite

  // ---------- combine G = R_b0 + i*R_b1, single inverse FFT-512 ----------
  #pragma unroll
  for(int rr=0;rr<8;rr++){
    int k1 = lane + 64*rr;
    Cre[k1] = pv0[rr].x - pv1[rr].y;
    Cim[k1] = pv0[rr].y + pv1[rr].x;
  }
  wsync();           // own-wave write->read ordering
  fft512_wave<1>(Cre, Cim, lane, twc, tws);
  // stage twiddle W_N^{+m1*myc}: base + 7-step recurrence
  cf w, st;
  {
    float sv,cv;
    __sincosf(4.793689960382698e-05f * (float)(lane*myc), &sv, &cv);
    w = {cv, sv};
    __sincosf(4.793689960382698e-05f * 64.f * (float)myc, &sv, &cv);
    st = {cv, sv};
  }
  #pragma unroll
  for(int rr=0;rr<8;rr++){
    int m1 = lane + 64*rr;
    cf r2 = cmul(cf{Cre[m1],Cim[m1]}, w);
    colp0[m1] = make_float2(r2.x, r2.y);
    w = cmul(w, st);
  }
}

// ---------------- K4: inverse stage-2 (IFFT-256 over k2), writes TWO rows ----------------
__global__ __launch_bounds__(256) void k4_inv2(
    const float2* __restrict__ Qws, float* __restrict__ dout, int cplx)
{
  __shared__ float reb[4384], imb[4384];
  __shared__ float twc[256], tws[256];
  int t = threadIdx.x;
  int bp = blockIdx.x >> 5;                 // row pair 0..31
  int m1b = (blockIdx.x & 31) << 4;
  int b0 = bp*2;
  {
    float sv, cv;
    __sincosf(0.0245436926061703f * (float)t, &sv, &cv); // +2*pi/256 * t
    twc[t]=cv; tws[t]=sv;
  }
  const float4* Qp = (const float4*)(Qws + ((size_t)b0<<17));
  #pragma unroll
  for(int it=0; it<8; ++it){
    int e = t + 256*it;
    int k2 = e >> 3, j = e & 7;
    float4 q = Qp[k2*256 + (m1b>>1) + j];
    int lb = k2*17 + 2*j;
    reb[lb+0]=q.x; imb[lb+0]=q.y;
    reb[lb+1]=q.z; imb[lb+1]=q.w;
  }
  __syncthreads();
  int f = t & 15, p = t >> 4;
  cf v[16];
  #pragma unroll
  for(int q=0;q<16;q++){ int k2=q*16+p; v[q].x=reb[k2*17+f]; v[q].y=imb[k2*17+f]; }
  fft16<1>(v);
  #pragma unroll
  for(int kq=1;kq<16;kq++){ int tt=(p*kq)&255; v[kq]=cmul(v[kq], cf{twc[tt], tws[tt]}); }
  __syncthreads();
  #pragma unroll
  for(int kq=0;kq<16;kq++){ reb[f*274+kq*17+p]=v[kq].x; imb[f*274+kq*17+p]=v[kq].y; }
  __syncthreads();
  #pragma unroll
  for(int pp=0;pp<16;pp++){ v[pp].x=reb[f*274+p*17+pp]; v[pp].y=imb[f*274+p*17+pp]; }
  fft16<1>(v);
  #pragma unroll
  for(int kp=0;kp<16;kp++){
    int m2 = kp*16 + p;
    size_t n = (size_t)(m1b + f) + (size_t)512*m2;
    size_t o0 = (size_t)b0*DIM + n;        // y.x -> read[b0], y.y -> read[b0+1]
    if(cplx==2){
      ((float2*)dout)[o0]       = make_float2(v[kp].x, 0.f);
      ((float2*)dout)[o0 + DIM] = make_float2(v[kp].y, 0.f);
    } else {
      dout[o0]       = v[kp].x;
      dout[o0 + DIM] = v[kp].y;
    }
  }
}

// ---------------- launch ----------------
extern "C" void kernel_launch(void* const* d_in, const int* in_sizes, int n_in,
                              void* d_out, int out_size, void* d_ws, size_t ws_size,
                              hipStream_t stream)
{
  (void)in_sizes; (void)n_in; (void)ws_size;
  const float* z    = (const float*)d_in[0];
  const float* tr   = (const float*)d_in[1];
  const float* ctrl = (const float*)d_in[2];
  float* dout = (float*)d_out;
  // complex64 outputs flattened as interleaved float32 -> out_size = 2*2*B*DIM + B + 1.
  int cplx = (out_size > 20000000) ? 2 : 1;
  unsigned* maxbits = (unsigned*)d_ws;
  float2* Bws = (float2*)((char*)d_ws + 256);   // 64 MiB intermediate, in-place through K3

  hipMemsetAsync(d_ws, 0, 4, stream);
  hipLaunchKernelGGL(k0_tail,  dim3(1),    dim3(128), 0, stream, dout, cplx);
  hipLaunchKernelGGL(k1_maxabs,dim3(1024), dim3(256), 0, stream, z, maxbits);
  hipLaunchKernelGGL(k2_fwd1,  dim3(2048), dim3(256), 0, stream,
                     z, tr, ctrl, maxbits, Bws, dout + (size_t)NROW*DIM*cplx, cplx);
  hipLaunchKernelGGL(k3_mid,   dim3(4096), dim3(128), 0, stream, Bws, ctrl, maxbits);
  hipLaunchKernelGGL(k4_inv2,  dim3(1024), dim3(256), 0, stream, Bws, dout, cplx);
}